// Round 1
// baseline (109.586 us; speedup 1.0000x reference)
//
#include <hip/hip_runtime.h>
#include <hip/hip_bf16.h>

// The reference network is degenerate: _adder2d returns -sum(|x-w|) <= 0
// for ALL inputs (sum of non-negatives is non-negative in fp32 too), and
// _block applies ReLU BEFORE BatchNorm, so relu(adder) == 0 identically.
// Every block therefore outputs the per-channel constant
//   bn_eval(0) = beta - mean * gamma / sqrt(var + eps),
// independent of x and of every weight tensor. Only bn8, fc_w, fc_b reach
// the output:
//   out[b][o] = fc_b[o] + sum_c (b8[c] - m8[c]*g8[c]/sqrt(v8[c]+eps)) * fc_w[o][c]
// and the row is identical for all 32 batch entries. This is an exact
// algebraic identity (holds for arbitrary input values), so we compute it
// directly: ~5 KFLOP instead of 7.6 GMAC.

#define EPS_F 1e-5f

__global__ __launch_bounds__(256) void VGG_83794811945245_kernel(
    const float* __restrict__ bn8,   // [4][512]: gamma, beta, mean, var
    const float* __restrict__ fc_w,  // [10][512]
    const float* __restrict__ fc_b,  // [10]
    float* __restrict__ out)         // [32][10]
{
    __shared__ float c8[512];
    __shared__ float logits[10];

    const int t = threadIdx.x;

    // Phase 1: per-channel constant after block 8
    for (int c = t; c < 512; c += 256) {
        float g = bn8[c];
        float b = bn8[512 + c];
        float m = bn8[1024 + c];
        float v = bn8[1536 + c];
        float inv = g / sqrtf(v + EPS_F);
        c8[c] = b - m * inv;
    }
    __syncthreads();

    // Phase 2: 10 dot-products of length 512, one per output class,
    // distributed over the 4 waves; 64-lane shuffle reduction each.
    const int wave = t >> 6;
    const int lane = t & 63;
    for (int o = wave; o < 10; o += 4) {
        float s = 0.0f;
        const float* wrow = fc_w + o * 512;
        #pragma unroll
        for (int k = 0; k < 8; ++k) {
            int c = lane + 64 * k;
            s += wrow[c] * c8[c];
        }
        #pragma unroll
        for (int off = 32; off > 0; off >>= 1)
            s += __shfl_down(s, off);
        if (lane == 0)
            logits[o] = s + fc_b[o];
    }
    __syncthreads();

    // Phase 3: broadcast the logits row to all 32 batch entries.
    for (int i = t; i < 320; i += 256) {
        out[i] = logits[i % 10];
    }
}

extern "C" void kernel_launch(void* const* d_in, const int* in_sizes, int n_in,
                              void* d_out, int out_size, void* d_ws, size_t ws_size,
                              hipStream_t stream) {
    // setup_inputs() dict order (w and bn interleaved per layer):
    //  0:x, 1:w1, 2:bn1, 3:w2, 4:bn2, 5:w3, 6:bn3, 7:w4, 8:bn4,
    //  9:w5, 10:bn5, 11:w6, 12:bn6, 13:w7, 14:bn7, 15:w8, 16:bn8,
    // 17:fc_w, 18:fc_b
    const float* bn8  = (const float*)d_in[16];
    const float* fc_w = (const float*)d_in[17];
    const float* fc_b = (const float*)d_in[18];
    float* out = (float*)d_out;

    VGG_83794811945245_kernel<<<1, 256, 0, stream>>>(bn8, fc_w, fc_b, out);
}